// Round 2
// baseline (440.179 us; speedup 1.0000x reference)
//
#include <hip/hip_runtime.h>
#include <hip/hip_bf16.h>

// GraphConvolutionLayer on MI355X (gfx950) — fused single-pass, LDS-lean version.
//   scale = 1/(rowsum(adj)+beta);  agg = adj@x + beta*x;  out = (scale*agg)@W + bias
// Design notes (round 2):
//   - Inner loop was LDS-bound (136 KB LDS traffic per 8 KB of adj) and the
//     runtime-indexed triple buffer forced compiler vmcnt drains (alias).
//   - Now: A staged as bf16 via reg-pack (halves A-frag reads; exact fp32
//     rowsum computed pre-pack by ALL waves), m32n32 wave tiles (halves B-frag
//     reads), and a hand-unrolled 3-phase pipeline with LITERAL buffer indices
//     so global_load_lds dests and ds_read sources are provably distinct.
//   - One raw s_barrier per K-step; counted vmcnt(4) (never 0 in main loop).
//     Staging issued AFTER the barrier: buffer (c+2)%3 was last read at step
//     s-1, two barriers before the overwrite -> race-free.

typedef __attribute__((ext_vector_type(8))) short  short8;
typedef __attribute__((ext_vector_type(4))) short  bf16x4;
typedef __attribute__((ext_vector_type(4))) float  floatx4;

#define N_NODES 8192
#define F_DIM   256
#define BK      64
#define NSTEPS  (N_NODES / BK)   // 128

#define ASYNC16(g, l)                                                          \
  __builtin_amdgcn_global_load_lds(                                           \
      (const __attribute__((address_space(1))) void*)(g),                     \
      (__attribute__((address_space(3))) void*)(l), 16, 0, 0)

// fp32 -> bf16 round-to-nearest-even (no NaN handling; inputs are finite)
__device__ __forceinline__ unsigned short f2bf(float f) {
  unsigned u = __float_as_uint(f);
  return (unsigned short)((u + 0x7FFFu + ((u >> 16) & 1u)) >> 16);
}

__device__ __forceinline__ short8 pack_bf16x8(floatx4 a, floatx4 b) {
  short8 r;
  r[0] = (short)f2bf(a.x);
  r[1] = (short)f2bf(a.y);
  r[2] = (short)f2bf(a.z);
  r[3] = (short)f2bf(a.w);
  r[4] = (short)f2bf(b.x);
  r[5] = (short)f2bf(b.y);
  r[6] = (short)f2bf(b.z);
  r[7] = (short)f2bf(b.w);
  return r;
}

// ---------------------------------------------------------------------------
// k1: fp32 [K][256] -> bf16 tiled [K/32][n16(16)][kg(4)][nl(16)][8]
// ---------------------------------------------------------------------------
__global__ __launch_bounds__(256) void tile_bf16_kernel(
    const float* __restrict__ src, unsigned short* __restrict__ dst, int K) {
  const int Nn = F_DIM;
  int cid = blockIdx.x * 256 + threadIdx.x;      // one 8-element chunk
  int per_kblk = Nn * 4;                         // 1024 chunks per 32-k block
  int kblk = cid / per_kblk;
  int rem  = cid - kblk * per_kblk;
  int n16 = rem >> 6;
  int kg  = (rem >> 4) & 3;
  int nl  = rem & 15;
  int n = n16 * 16 + nl;
  int k = kblk * 32 + kg * 8;
  const float* s = src + (size_t)k * Nn + n;
  floatx4 v0, v1;
  v0.x = s[0];
  v0.y = s[(size_t)Nn];
  v0.z = s[(size_t)2 * Nn];
  v0.w = s[(size_t)3 * Nn];
  v1.x = s[(size_t)4 * Nn];
  v1.y = s[(size_t)5 * Nn];
  v1.z = s[(size_t)6 * Nn];
  v1.w = s[(size_t)7 * Nn];
  *(short8*)(dst + (size_t)cid * 8) = pack_bf16x8(v0, v1);
}

// ---------------------------------------------------------------------------
// k2: fused  agg + rowsum + scale + W-GEMM
// grid 256 blocks x 512 threads (8 waves, wave tile m32 x n32).
// LDS: A bf16 3 x 4 KB @ 0 | B bf16 3 x 32 KB @ 12288  => 110592 B total.
// Epilogue overlays: G bf16 16 KB @ 0, x fp32 32 KB @ 16384, scale/beta @ 49152.
// ---------------------------------------------------------------------------
#define AB(i) (smem + (i) * 4096)
#define BB(i) (smem + 12288 + (i) * 32768)

#define STAGE_B(sidx, c)                                                       \
  {                                                                            \
    const unsigned short* bs_ = bsrc + (size_t)(sidx) * 16384;                 \
    char* bd_ = BB(c) + (w << 10);                                             \
    ASYNC16(bs_,          bd_);                                                \
    ASYNC16(bs_ +  4096,  bd_ +  8192);                                        \
    ASYNC16(bs_ +  8192,  bd_ + 16384);                                        \
    ASYNC16(bs_ + 12288,  bd_ + 24576);                                        \
  }

#define WRITE_A(c)                                                             \
  {                                                                            \
    rsum += (areg.x + areg.y) + (areg.z + areg.w);                             \
    bf16x4 pk_;                                                                \
    pk_[0] = (short)f2bf(areg.x);                                              \
    pk_[1] = (short)f2bf(areg.y);                                              \
    pk_[2] = (short)f2bf(areg.z);                                              \
    pk_[3] = (short)f2bf(areg.w);                                              \
    *(bf16x4*)(AB(c) + awoff) = pk_;                                           \
  }

#define MFMA16(a, b, c) __builtin_amdgcn_mfma_f32_16x16x32_bf16(a, b, c, 0, 0, 0)

#define COMPUTE(c)                                                             \
  {                                                                            \
    const char* Ab_ = AB(c);                                                   \
    const char* Bb_ = BB(c);                                                   \
    short8 a00 = *(const short8*)(Ab_ + aoff00);                               \
    short8 a01 = *(const short8*)(Ab_ + aoff01);                               \
    short8 a10 = *(const short8*)(Ab_ + aoff10);                               \
    short8 a11 = *(const short8*)(Ab_ + aoff11);                               \
    short8 b00 = *(const short8*)(Bb_ + boff00);                               \
    short8 b01 = *(const short8*)(Bb_ + boff01);                               \
    short8 b10 = *(const short8*)(Bb_ + boff10);                               \
    short8 b11 = *(const short8*)(Bb_ + boff11);                               \
    acc[0][0] = MFMA16(a00, b00, acc[0][0]);                                   \
    acc[1][0] = MFMA16(a01, b00, acc[1][0]);                                   \
    acc[0][1] = MFMA16(a00, b01, acc[0][1]);                                   \
    acc[1][1] = MFMA16(a01, b01, acc[1][1]);                                   \
    acc[0][0] = MFMA16(a10, b10, acc[0][0]);                                   \
    acc[1][0] = MFMA16(a11, b10, acc[1][0]);                                   \
    acc[0][1] = MFMA16(a10, b11, acc[0][1]);                                   \
    acc[1][1] = MFMA16(a11, b11, acc[1][1]);                                   \
  }

// One pipelined K-step: computes step `sidx` (≡ c mod 3), packs A(sidx+1),
// prefetches A(sidx+2) to reg and stages B(sidx+2).
#define FULL_ITER(sidx, c)                                                     \
  asm volatile("s_waitcnt vmcnt(4)" ::: "memory");                             \
  WRITE_A((c + 1) % 3);                                                        \
  areg = *(const floatx4*)(asrc + (size_t)((sidx) + 2) * BK);                  \
  asm volatile("s_waitcnt lgkmcnt(0)" ::: "memory");                           \
  asm volatile("s_barrier" ::: "memory");                                      \
  STAGE_B((sidx) + 2, (c + 2) % 3);                                           \
  COMPUTE(c);

__global__ __launch_bounds__(512, 2) void fused_kernel(
    const float* __restrict__ adj, const unsigned short* __restrict__ xbt,
    const float* __restrict__ x, const float* __restrict__ beta,
    const float* __restrict__ bias, const unsigned short* __restrict__ wbt,
    float* __restrict__ out) {
  __shared__ __attribute__((aligned(16))) char smem[110592];
  float* sscale = (float*)(smem + 49152);
  float* sbeta  = (float*)(smem + 49280);

  const int tid = threadIdx.x;
  const int w   = tid >> 6;      // 0..7
  const int l   = tid & 63;
  const int kq  = l >> 4;        // MFMA k-quad
  const int ml  = l & 15;
  const int r7  = ml & 7;
  const int m0  = blockIdx.x * 32;

  // ---- staging geometry ----
  // A reg-stage: thread t owns (row = t>>4, 4 floats at kc = t&15); packs to
  // bf16 and ds_writes 8 B at chunk (kc>>1), half (kc&1), XOR-swizzled.
  const int arow = tid >> 4;
  const int akc  = tid & 15;
  const float* asrc = adj + (size_t)(m0 + arow) * N_NODES + akc * 4;
  const int awoff = arow * 128 + ((((akc >> 1) ^ (arow & 7))) << 4) + (akc & 1) * 8;
  // B: xbt MFMA-tiled; one step = 2 kblks = 32 KB contiguous, copied linearly.
  const unsigned short* bsrc = xbt + (size_t)tid * 8;

  // A-frag byte offsets (bf16 [32][64], 16B-chunk XOR swizzle): frag (kb,mf):
  // row = mf*16+ml, chunk = kb*4+kq stored at chunk^(row&7).
  const int aoff00 = (0 * 16 + ml) * 128 + (((0 * 4 + kq) ^ r7) << 4);
  const int aoff01 = (1 * 16 + ml) * 128 + (((0 * 4 + kq) ^ r7) << 4);
  const int aoff10 = (0 * 16 + ml) * 128 + (((1 * 4 + kq) ^ r7) << 4);
  const int aoff11 = (1 * 16 + ml) * 128 + (((1 * 4 + kq) ^ r7) << 4);
  // B-frag byte offsets: frag (kb,nf): n16 = w*2+nf.
  const int boff00 = 0 * 16384 + (w * 2 + 0) * 1024 + kq * 256 + ml * 16;
  const int boff01 = 0 * 16384 + (w * 2 + 1) * 1024 + kq * 256 + ml * 16;
  const int boff10 = 1 * 16384 + (w * 2 + 0) * 1024 + kq * 256 + ml * 16;
  const int boff11 = 1 * 16384 + (w * 2 + 1) * 1024 + kq * 256 + ml * 16;

  floatx4 acc[2][2];
  const floatx4 zf4 = {0.f, 0.f, 0.f, 0.f};
  acc[0][0] = zf4; acc[0][1] = zf4; acc[1][0] = zf4; acc[1][1] = zf4;
  float rsum = 0.f;
  floatx4 areg;

  // ---- prologue: fill 3-deep pipeline ----
  areg = *(const floatx4*)(asrc);                 // a0
  STAGE_B(0, 0);
  asm volatile("s_waitcnt vmcnt(4)" ::: "memory");  // a0 ready (4 newest = B0)
  WRITE_A(0);
  areg = *(const floatx4*)(asrc + BK);            // a1
  STAGE_B(1, 1);
  asm volatile("s_waitcnt vmcnt(4)" ::: "memory");  // a1 + B0 forced
  WRITE_A(1);
  areg = *(const floatx4*)(asrc + 2 * BK);        // a2
  asm volatile("s_waitcnt lgkmcnt(0)" ::: "memory");
  asm volatile("s_barrier" ::: "memory");           // publish A0, A1, B0
  STAGE_B(2, 2);
  COMPUTE(0);

  // ---- main loop: s = 1..123, static buffer indices ----
  for (int t = 0; t < 41; ++t) {
    const int s0 = 3 * t + 1;
    FULL_ITER(s0,     1);
    FULL_ITER(s0 + 1, 2);
    FULL_ITER(s0 + 2, 0);
  }
  FULL_ITER(124, 1);
  FULL_ITER(125, 2);
  // s = 126: pack A(127); nothing left to prefetch
  asm volatile("s_waitcnt vmcnt(4)" ::: "memory");  // a127 forced (4 newest = B127)
  WRITE_A(1);
  asm volatile("s_waitcnt lgkmcnt(0)" ::: "memory");
  asm volatile("s_barrier" ::: "memory");
  COMPUTE(0);
  // s = 127
  asm volatile("s_waitcnt vmcnt(0)" ::: "memory");  // B127 landed
  asm volatile("s_barrier" ::: "memory");
  COMPUTE(1);

  __syncthreads();   // drain; LDS reusable by epilogue overlays

  // ---- epilogue ----
  // stage x-tile (32 rows x 256 fp32 = 32 KB) @ smem+16384, linear
  {
    const float* xs = x + (size_t)m0 * F_DIM + tid * 4;
    char* xd = smem + 16384 + (w << 10);
#pragma unroll
    for (int q = 0; q < 4; ++q) ASYNC16(xs + q * 2048, xd + q * 8192);
  }
  // exact fp32 rowsum: thread partial covers (row = w*4 + (l>>4)); reduce the
  // 16 lanes of each row-group.
  {
    float rs = rsum;
    rs += __shfl_xor(rs, 1);
    rs += __shfl_xor(rs, 2);
    rs += __shfl_xor(rs, 4);
    rs += __shfl_xor(rs, 8);
    if ((l & 15) == 0) {
      int row = w * 4 + (l >> 4);
      float b = beta[m0 + row];
      sbeta[row]  = b;
      sscale[row] = 1.0f / (rs + b);
    }
  }
  __syncthreads();   // x landed (vmcnt drained), scale/beta visible

  // g = scale*(acc + beta*x) -> bf16 -> G @ smem, 16B-chunk XOR swizzle by row
  const float* xl = (const float*)(smem + 16384);
  unsigned short* G = (unsigned short*)smem;
#pragma unroll
  for (int nf = 0; nf < 2; ++nf) {
    int col = w * 32 + nf * 16 + ml;
    int chunk = col >> 3;            // 0..31
#pragma unroll
    for (int mf = 0; mf < 2; ++mf)
#pragma unroll
      for (int r = 0; r < 4; ++r) {
        int row = mf * 16 + kq * 4 + r;   // C/D layout: col=lane&15, row=quad*4+reg
        float g = sscale[row] * (acc[mf][nf][r] + sbeta[row] * xl[row * F_DIM + col]);
        int slot = (chunk & 24) | ((chunk ^ row) & 7);
        G[row * 256 + slot * 8 + (col & 7)] = f2bf(g);
      }
  }
  __syncthreads();

  // GEMM2: out = g @ W + bias  (W-frags straight from L2-hot wbt)
  floatx4 acc2[2][2];
  acc2[0][0] = zf4; acc2[0][1] = zf4; acc2[1][0] = zf4; acc2[1][1] = zf4;
#pragma unroll
  for (int s2 = 0; s2 < 8; ++s2) {
    int c = s2 * 4 + kq;
    int sl = (c & 24) | ((c ^ ml) & 7);   // rows ml and 16+ml share low-3 XOR
    short8 ag0 = *(const short8*)(G + (ml)      * 256 + sl * 8);
    short8 ag1 = *(const short8*)(G + (16 + ml) * 256 + sl * 8);
    const unsigned short* wb = wbt + s2 * 8192 + (w * 2) * 512 + kq * 128 + ml * 8;
    short8 wv0 = *(const short8*)(wb);
    short8 wv1 = *(const short8*)(wb + 512);
    acc2[0][0] = MFMA16(ag0, wv0, acc2[0][0]);
    acc2[1][0] = MFMA16(ag1, wv0, acc2[1][0]);
    acc2[0][1] = MFMA16(ag0, wv1, acc2[0][1]);
    acc2[1][1] = MFMA16(ag1, wv1, acc2[1][1]);
  }
#pragma unroll
  for (int nf = 0; nf < 2; ++nf) {
    int col = w * 32 + nf * 16 + ml;
    float bv = bias[col];
#pragma unroll
    for (int mf = 0; mf < 2; ++mf)
#pragma unroll
      for (int r = 0; r < 4; ++r) {
        int row = m0 + mf * 16 + kq * 4 + r;
        out[(size_t)row * F_DIM + col] = acc2[mf][nf][r] + bv;
      }
  }
}

// ---------------------------------------------------------------------------
extern "C" void kernel_launch(void* const* d_in, const int* in_sizes, int n_in,
                              void* d_out, int out_size, void* d_ws, size_t ws_size,
                              hipStream_t stream) {
  const float* x    = (const float*)d_in[0];  // [8192][256]
  const float* adj  = (const float*)d_in[1];  // [8192][8192]
  const float* kern = (const float*)d_in[2];  // [256][256]
  const float* bias = (const float*)d_in[3];  // [256]
  const float* beta = (const float*)d_in[4];  // [8192]
  float* out = (float*)d_out;

  char* ws = (char*)d_ws;
  unsigned short* xbt = (unsigned short*)ws;                 // 4 MB
  unsigned short* wbt = xbt + (size_t)N_NODES * F_DIM;       // 128 KB

  tile_bf16_kernel<<<(N_NODES * F_DIM / 8) / 256, 256, 0, stream>>>(x, xbt, N_NODES);
  tile_bf16_kernel<<<(F_DIM * F_DIM / 8) / 256, 256, 0, stream>>>(kern, wbt, F_DIM);
  fused_kernel<<<256, 512, 0, stream>>>(adj, xbt, x, beta, bias, wbt, out);
}

// Round 4
// 432.638 us; speedup vs baseline: 1.0174x; 1.0174x over previous
//
#include <hip/hip_runtime.h>
#include <hip/hip_bf16.h>

// GraphConvolutionLayer on MI355X (gfx950) — round-0 two-stage structure with a
// counted-vmcnt triple-buffered stage1 (one barrier per K-step, never drains
// vmcnt to 0 in the main loop).
//   scale = 1/(rowsum(adj)+beta);  agg = adj@x + beta*x;  out = (scale*agg)@W + bias
// Evidence base (R0-R2): 1-block/CU deep-pipelined fused kernels are
// latency-bound at lockstep barriers (R2: 11% HBM, 7.6% MfmaUtil, 1.37us/step).
// Round-0's 2-blocks/CU global_load_lds structure was fastest. R3/R4 keeps that
// geometry (M=64, KS=4, BK=32, grid 512, 256 thr) and upgrades only the loop:
//   - 3 LDS buffers (72 KB -> still 2 blocks/CU), literal buffer indices.
//   - Per step: {s_waitcnt vmcnt(6) lgkmcnt(0); s_barrier} -> stage(s+2) ->
//     compute(s). Every load has 2 full steps of slack; no reg round trips.
//   - lgkmcnt(0) fused with the barrier: all waves' ds_reads retire before any
//     wave overwrites the (s+2)%3 buffer (last read at s-1, two barriers ago).
// R4 = R3 resubmission after a broker-side "container failed twice" (audit
// found no hangable construct: uniform barriers, bounded waitcnts, race-free
// buffer rotation, no disallowed host calls).

typedef __attribute__((ext_vector_type(8))) short  short8;
typedef __attribute__((ext_vector_type(4))) float  floatx4;

#define N_NODES 8192
#define F_DIM   256

#define ASYNC16(g, l)                                                          \
  __builtin_amdgcn_global_load_lds(                                           \
      (const __attribute__((address_space(1))) void*)(g),                     \
      (__attribute__((address_space(3))) void*)(l), 16, 0, 0)

// fp32 -> bf16 round-to-nearest-even (no NaN handling; inputs are finite)
__device__ __forceinline__ unsigned short f2bf(float f) {
  unsigned u = __float_as_uint(f);
  return (unsigned short)((u + 0x7FFFu + ((u >> 16) & 1u)) >> 16);
}

__device__ __forceinline__ short8 pack_bf16x8(floatx4 a, floatx4 b) {
  short8 r;
  r[0] = (short)f2bf(a.x);
  r[1] = (short)f2bf(a.y);
  r[2] = (short)f2bf(a.z);
  r[3] = (short)f2bf(a.w);
  r[4] = (short)f2bf(b.x);
  r[5] = (short)f2bf(b.y);
  r[6] = (short)f2bf(b.z);
  r[7] = (short)f2bf(b.w);
  return r;
}

// ---------------------------------------------------------------------------
// k1: fp32 [K][256] -> bf16 tiled [K/32][n16(16)][kg(4)][nl(16)][8]
// ---------------------------------------------------------------------------
__global__ __launch_bounds__(256) void tile_bf16_kernel(
    const float* __restrict__ src, unsigned short* __restrict__ dst, int K) {
  const int Nn = F_DIM;
  int cid = blockIdx.x * 256 + threadIdx.x;      // one 8-element chunk
  int per_kblk = Nn * 4;                         // 1024 chunks per 32-k block
  int kblk = cid / per_kblk;
  int rem  = cid - kblk * per_kblk;
  int n16 = rem >> 6;
  int kg  = (rem >> 4) & 3;
  int nl  = rem & 15;
  int n = n16 * 16 + nl;
  int k = kblk * 32 + kg * 8;
  const float* s = src + (size_t)k * Nn + n;
  floatx4 v0, v1;
  v0.x = s[0];
  v0.y = s[(size_t)Nn];
  v0.z = s[(size_t)2 * Nn];
  v0.w = s[(size_t)3 * Nn];
  v1.x = s[(size_t)4 * Nn];
  v1.y = s[(size_t)5 * Nn];
  v1.z = s[(size_t)6 * Nn];
  v1.w = s[(size_t)7 * Nn];
  *(short8*)(dst + (size_t)cid * 8) = pack_bf16x8(v0, v1);
}

// ---------------------------------------------------------------------------
// k2: stage1 — partial agg (adj @ x) + partial rowsums, K-split KS
// grid dim3(128, KS), block 256 (4 waves). LDS 72 KB -> 2 blocks/CU.
// Buffers: A fp32 3 x 8 KB @ 0 | B bf16 3 x 16 KB @ 24576.
// ---------------------------------------------------------------------------
#define MFMA16(a, b, c) __builtin_amdgcn_mfma_f32_16x16x32_bf16(a, b, c, 0, 0, 0)

#define STAGE(s, c)                                                            \
  {                                                                            \
    ASYNC16(agp0 + (size_t)(s) * 32, smem + (c) * 8192 + (w * 2) * 1024);      \
    ASYNC16(agp1 + (size_t)(s) * 32, smem + (c) * 8192 + (w * 2 + 1) * 1024);  \
    const unsigned short* bs_ = bgp + (size_t)(s) * 8192;                      \
    char* bd_ = smem + 24576 + (c) * 16384 + (w * 4) * 1024;                   \
    ASYNC16(bs_,        bd_);                                                  \
    ASYNC16(bs_ +  512, bd_ + 1024);                                           \
    ASYNC16(bs_ + 1024, bd_ + 2048);                                           \
    ASYNC16(bs_ + 1536, bd_ + 3072);                                           \
  }

#define COMPUTE(c)                                                             \
  {                                                                            \
    const float* At_ = (const float*)(smem + (c) * 8192);                      \
    const unsigned short* Bt_ =                                                \
        (const unsigned short*)(smem + 24576 + (c) * 16384);                   \
    short8 af[4];                                                              \
    _Pragma("unroll") for (int mf = 0; mf < 4; ++mf) {                         \
      floatx4 a0 = *(const floatx4*)(At_ + aoff0[mf]);                         \
      floatx4 a1 = *(const floatx4*)(At_ + aoff1[mf]);                         \
      if (w == 0)  /* fused rowsum: wave0 reads the whole A-tile anyway */     \
        rsum[mf] += (a0.x + a0.y + a0.z + a0.w) + (a1.x + a1.y + a1.z + a1.w); \
      af[mf] = pack_bf16x8(a0, a1);                                            \
    }                                                                          \
    _Pragma("unroll") for (int nf = 0; nf < 4; ++nf) {                         \
      short8 bv = *(const short8*)(Bt_ + boff[nf]);                            \
      _Pragma("unroll") for (int mf = 0; mf < 4; ++mf)                         \
        acc[mf][nf] = MFMA16(af[mf], bv, acc[mf][nf]);                         \
    }                                                                          \
  }

// One pipelined K-step: publish buffer c, stage step s+2 into cn=(c+2)%3,
// compute step s from buffer c. vmcnt(6) = exactly one step's loads in flight.
#define ITER(s, c, cn)                                                         \
  asm volatile("s_waitcnt vmcnt(6) lgkmcnt(0)\n\ts_barrier" ::: "memory");     \
  STAGE((s) + 2, cn);                                                          \
  COMPUTE(c);

template <int KS>
__global__ __launch_bounds__(256, 2) void stage1_kernel(
    const float* __restrict__ adj, const unsigned short* __restrict__ xbt,
    float* __restrict__ part, float* __restrict__ rsp) {
  constexpr int KSTEPS = (N_NODES / KS) / 32;     // 64 (KS=4) / 256 (KS=1)
  constexpr int TMAIN  = (KSTEPS - 4) / 3;        // 20 / 84 (both exact)
  static_assert(TMAIN * 3 + 4 == KSTEPS, "KSTEPS-4 must be divisible by 3");

  __shared__ __attribute__((aligned(16))) char smem[73728];

  const int tid = threadIdx.x;
  const int w  = tid >> 6;
  const int l  = tid & 63;
  const int kq = l >> 4;       // MFMA k-quad
  const int ml = l & 15;
  const int m0 = blockIdx.x * 64;
  const int ks = blockIdx.y;
  const int kbeg = ks * (N_NODES / KS);

  // A staging: wave w covers chunks 2w,2w+1 (8 rows each). lane: row=c*8+l/8,
  // source col-group XOR-swizzled so frag reads are ~conflict-free.
  const int arow = w * 16 + (l >> 3);
  const int srcg = (l & 7) ^ ((l >> 3) & 7);
  const float* agp0 = adj + (size_t)(m0 + arow) * N_NODES + kbeg + srcg * 4;
  const float* agp1 = agp0 + (size_t)8 * N_NODES;
  // B staging: 16 KB contiguous per k-block; wave w covers chunks 4w..4w+3
  const unsigned short* bgp =
      xbt + (size_t)(kbeg / 32) * (32 * F_DIM) + (w * 4) * 512 + l * 8;

  int aoff0[4], aoff1[4], boff[4];
#pragma unroll
  for (int mf = 0; mf < 4; ++mf) {
    int m = mf * 16 + ml;
    aoff0[mf] = m * 32 + (((kq * 2)     ^ (m & 7)) * 4);
    aoff1[mf] = m * 32 + (((kq * 2 + 1) ^ (m & 7)) * 4);
  }
#pragma unroll
  for (int nf = 0; nf < 4; ++nf)
    boff[nf] = (w * 4 + nf) * 512 + kq * 128 + ml * 8;

  floatx4 acc[4][4];
  const floatx4 zf4 = {0.f, 0.f, 0.f, 0.f};
#pragma unroll
  for (int mf = 0; mf < 4; ++mf)
#pragma unroll
    for (int nf = 0; nf < 4; ++nf) acc[mf][nf] = zf4;
  float rsum[4] = {0.f, 0.f, 0.f, 0.f};

  // ---- prologue: stage steps 0,1 into buffers 0,1 (12 loads in flight) ----
  STAGE(0, 0);
  STAGE(1, 1);

  // ---- main loop: steps 0..KSTEPS-5, literal buffer indices ----
  for (int t = 0; t < TMAIN; ++t) {
    const int s0 = 3 * t;
    ITER(s0,     0, 2);
    ITER(s0 + 1, 1, 0);
    ITER(s0 + 2, 2, 1);
  }
  ITER(KSTEPS - 4, 0, 2);   // stages KSTEPS-2 -> buf (KSTEPS-2)%3 == 2
  ITER(KSTEPS - 3, 1, 0);   // stages KSTEPS-1 -> buf 0
  // tail: nothing left to stage
  asm volatile("s_waitcnt vmcnt(6) lgkmcnt(0)\n\ts_barrier" ::: "memory");
  COMPUTE(2);               // step KSTEPS-2
  asm volatile("s_waitcnt vmcnt(0) lgkmcnt(0)\n\ts_barrier" ::: "memory");
  COMPUTE(0);               // step KSTEPS-1

  // epilogue: C/D layout col=lane&15, row=quad*4+reg (m89-verified)
  float* pout = part + (size_t)ks * N_NODES * F_DIM;
#pragma unroll
  for (int mf = 0; mf < 4; ++mf)
#pragma unroll
    for (int nf = 0; nf < 4; ++nf) {
      int col = w * 64 + nf * 16 + ml;
#pragma unroll
      for (int r = 0; r < 4; ++r) {
        int row = m0 + mf * 16 + kq * 4 + r;
        pout[(size_t)row * F_DIM + col] = acc[mf][nf][r];
      }
    }

  if (w == 0) {
#pragma unroll
    for (int mf = 0; mf < 4; ++mf) {
      float v = rsum[mf];
      v += __shfl_xor(v, 16);
      v += __shfl_xor(v, 32);
      if (kq == 0) rsp[ks * N_NODES + m0 + mf * 16 + ml] = v;
    }
  }
}

#undef ITER
#undef COMPUTE
#undef STAGE

// ---------------------------------------------------------------------------
// k3: stage2 — out = (scale * (sum partials + beta*x)) @ W + bias
// grid: 256 blocks (32 rows each), block 256
// part may alias out when KS==1 (block only rewrites rows it alone reads)
// ---------------------------------------------------------------------------
template <int KS>
__global__ __launch_bounds__(256, 2) void stage2_kernel(
    const float* part, const float* __restrict__ rsp,
    const float* __restrict__ x, const float* __restrict__ beta,
    const float* __restrict__ bias, const unsigned short* __restrict__ wbt,
    float* out) {
  __shared__ unsigned short At[32 * 32];     // 2 KB bf16, grp ^ (row&3) swizzle
  __shared__ unsigned short Bt[32 * F_DIM];  // 16 KB
  __shared__ float sscale[32];
  __shared__ float sbeta[32];

  const int tid = threadIdx.x;
  const int w  = tid >> 6;
  const int l  = tid & 63;
  const int kq = l >> 4;
  const int ml = l & 15;
  const int m0 = blockIdx.x * 32;

  if (tid < 32) {
    float rs = 0.f;
#pragma unroll
    for (int p = 0; p < KS; ++p) rs += rsp[p * N_NODES + m0 + tid];
    float b = beta[m0 + tid];
    sbeta[tid]  = b;
    sscale[tid] = 1.0f / (rs + b);
  }
  __syncthreads();

  floatx4 acc[2][4];
  const floatx4 zf4 = {0.f, 0.f, 0.f, 0.f};
#pragma unroll
  for (int mf = 0; mf < 2; ++mf)
#pragma unroll
    for (int nf = 0; nf < 4; ++nf) acc[mf][nf] = zf4;

  const unsigned short* bgp = wbt + (w * 4) * 512 + l * 8;
  unsigned short* bldst = Bt + (w * 4) * 512;

  for (int s = 0; s < 8; ++s) {
    ASYNC16(bgp,        bldst);
    ASYNC16(bgp +  512, bldst +  512);
    ASYNC16(bgp + 1024, bldst + 1024);
    ASYNC16(bgp + 1536, bldst + 1536);
    bgp += 32 * F_DIM;

    if (tid < 128) {  // waves 0-1 build the A-tile (wave-uniform branch)
      int r = tid >> 2, g = tid & 3;
      size_t off = (size_t)(m0 + r) * F_DIM + s * 32 + g * 8;
      floatx4 v0 = *(const floatx4*)(x + off);
      floatx4 v1 = *(const floatx4*)(x + off + 4);
      float bb = sbeta[r];
      v0 *= bb; v1 *= bb;
#pragma unroll
      for (int p = 0; p < KS; ++p) {
        const float* pp = part + (size_t)p * N_NODES * F_DIM + off;
        v0 += *(const floatx4*)pp;
        v1 += *(const floatx4*)(pp + 4);
      }
      float sc = sscale[r];
      v0 *= sc; v1 *= sc;
      *(short8*)(At + r * 32 + ((g ^ (r & 3)) * 8)) = pack_bf16x8(v0, v1);
    }
    __syncthreads();

    short8 af[2];
#pragma unroll
    for (int mf = 0; mf < 2; ++mf) {
      int m = mf * 16 + ml;
      af[mf] = *(const short8*)(At + m * 32 + ((kq ^ (m & 3)) * 8));
    }
#pragma unroll
    for (int nf = 0; nf < 4; ++nf) {
      short8 bv = *(const short8*)(Bt + (w * 4 + nf) * 512 + kq * 128 + ml * 8);
#pragma unroll
      for (int mf = 0; mf < 2; ++mf)
        acc[mf][nf] = MFMA16(af[mf], bv, acc[mf][nf]);
    }
    __syncthreads();
  }

#pragma unroll
  for (int nf = 0; nf < 4; ++nf) {
    int col = w * 64 + nf * 16 + ml;
    float bv = bias[col];
#pragma unroll
    for (int mf = 0; mf < 2; ++mf)
#pragma unroll
      for (int r = 0; r < 4; ++r) {
        int row = m0 + mf * 16 + kq * 4 + r;
        out[(size_t)row * F_DIM + col] = acc[mf][nf][r] + bv;
      }
  }
}

// ---------------------------------------------------------------------------
extern "C" void kernel_launch(void* const* d_in, const int* in_sizes, int n_in,
                              void* d_out, int out_size, void* d_ws, size_t ws_size,
                              hipStream_t stream) {
  const float* x    = (const float*)d_in[0];  // [8192][256]
  const float* adj  = (const float*)d_in[1];  // [8192][8192]
  const float* kern = (const float*)d_in[2];  // [256][256]
  const float* bias = (const float*)d_in[3];  // [256]
  const float* beta = (const float*)d_in[4];  // [8192]
  float* out = (float*)d_out;

  char* ws = (char*)d_ws;
  unsigned short* xbt = (unsigned short*)ws;                 // 4 MB
  unsigned short* wbt = xbt + (size_t)N_NODES * F_DIM;       // 128 KB
  float* rsp  = (float*)(wbt + F_DIM * F_DIM);               // 128 KB (KS<=4)
  float* part = (float*)((char*)rsp + 4 * N_NODES * sizeof(float));

  const size_t base    = (size_t)N_NODES * F_DIM * 2 + (size_t)F_DIM * F_DIM * 2 +
                         4 * (size_t)N_NODES * 4;
  const size_t part_sz = (size_t)N_NODES * F_DIM * 4;        // 8 MB per split

  tile_bf16_kernel<<<(N_NODES * F_DIM / 8) / 256, 256, 0, stream>>>(x, xbt, N_NODES);
  tile_bf16_kernel<<<(F_DIM * F_DIM / 8) / 256, 256, 0, stream>>>(kern, wbt, F_DIM);

  if (ws_size >= base + 4 * part_sz) {
    stage1_kernel<4><<<dim3(128, 4), 256, 0, stream>>>(adj, xbt, part, rsp);
    stage2_kernel<4><<<256, 256, 0, stream>>>(part, rsp, x, beta, bias, wbt, out);
  } else {
    // fallback: aggregate lives in d_out; stage2 rewrites it in place (row-local)
    stage1_kernel<1><<<dim3(128, 1), 256, 0, stream>>>(adj, xbt, out, rsp);
    stage2_kernel<1><<<256, 256, 0, stream>>>(out, rsp, x, beta, bias, wbt, out);
  }
}

// Round 5
// 428.522 us; speedup vs baseline: 1.0272x; 1.0096x over previous
//
#include <hip/hip_runtime.h>
#include <hip/hip_bf16.h>

// GraphConvolutionLayer on MI355X (gfx950) — fused single-pass, LDS-traffic-lean.
//   scale = 1/(rowsum(adj)+beta);  agg = adj@x + beta*x;  out = (scale*agg)@W + bias
// Evidence (R0-R4): two-stage @2blk/CU = 432 us regardless of pipelining (R4=R0);
// fused @1blk/CU (R1) = 417 us, limited by LDS BW (~136 KB LDS traffic per 8 KB
// of adj: fp32 A-frags re-read by all waves + B staged and read 2x). This round:
//   - B frags load DIRECTLY from L2-hot xbt into regs (double-buffered, 1 step
//     ahead); 1Mx8N wave split so each B-frag is read exactly once
//     (256 blocks x 4 MB = 1.05 GB L2 traffic ~ 30 us aggregate, under floor).
//   - A staged as BF16 via reg-pack (load dwordx4 at iter s for step s+2 ->
//     2 full steps of latency slack; pack once, not per-wave), XOR-swizzled
//     chunks, 3 x 4 KB buffers with literal indices.
//   - Per step LDS: 4 KB write + 32 KB frag reads (~300 cyc) vs 800-cyc HBM
//     budget -> HBM-paced. Only manual asm: {lgkmcnt(0); s_barrier}/step.
//     All vmcnt waits are compiler-counted (no drain-to-0, no manual vmcnt).
//   - Exact fp32 rowsum accumulated pre-pack per thread (row = tid>>4),
//     16-lane shuffle-reduced in the epilogue.
// Epilogue (x-stage, scale/beta, G-swizzle, GEMM2 vs wbt) is the R2-verified
// 1x8/2x2 mapping, copied verbatim.

typedef __attribute__((ext_vector_type(8))) short  short8;
typedef __attribute__((ext_vector_type(4))) short  bf16x4;
typedef __attribute__((ext_vector_type(4))) float  floatx4;

#define N_NODES 8192
#define F_DIM   256
#define BK      64
#define NSTEPS  (N_NODES / BK)   // 128

#define ASYNC16(g, l)                                                          \
  __builtin_amdgcn_global_load_lds(                                           \
      (const __attribute__((address_space(1))) void*)(g),                     \
      (__attribute__((address_space(3))) void*)(l), 16, 0, 0)

// fp32 -> bf16 round-to-nearest-even (no NaN handling; inputs are finite)
__device__ __forceinline__ unsigned short f2bf(float f) {
  unsigned u = __float_as_uint(f);
  return (unsigned short)((u + 0x7FFFu + ((u >> 16) & 1u)) >> 16);
}

__device__ __forceinline__ short8 pack_bf16x8(floatx4 a, floatx4 b) {
  short8 r;
  r[0] = (short)f2bf(a.x);
  r[1] = (short)f2bf(a.y);
  r[2] = (short)f2bf(a.z);
  r[3] = (short)f2bf(a.w);
  r[4] = (short)f2bf(b.x);
  r[5] = (short)f2bf(b.y);
  r[6] = (short)f2bf(b.z);
  r[7] = (short)f2bf(b.w);
  return r;
}

// ---------------------------------------------------------------------------
// k1: fp32 [K][256] -> bf16 tiled [K/32][n16(16)][kg(4)][nl(16)][8]
// ---------------------------------------------------------------------------
__global__ __launch_bounds__(256) void tile_bf16_kernel(
    const float* __restrict__ src, unsigned short* __restrict__ dst, int K) {
  const int Nn = F_DIM;
  int cid = blockIdx.x * 256 + threadIdx.x;      // one 8-element chunk
  int per_kblk = Nn * 4;                         // 1024 chunks per 32-k block
  int kblk = cid / per_kblk;
  int rem  = cid - kblk * per_kblk;
  int n16 = rem >> 6;
  int kg  = (rem >> 4) & 3;
  int nl  = rem & 15;
  int n = n16 * 16 + nl;
  int k = kblk * 32 + kg * 8;
  const float* s = src + (size_t)k * Nn + n;
  floatx4 v0, v1;
  v0.x = s[0];
  v0.y = s[(size_t)Nn];
  v0.z = s[(size_t)2 * Nn];
  v0.w = s[(size_t)3 * Nn];
  v1.x = s[(size_t)4 * Nn];
  v1.y = s[(size_t)5 * Nn];
  v1.z = s[(size_t)6 * Nn];
  v1.w = s[(size_t)7 * Nn];
  *(short8*)(dst + (size_t)cid * 8) = pack_bf16x8(v0, v1);
}

// ---------------------------------------------------------------------------
// k2: fused  agg + rowsum + scale + W-GEMM
// grid 256 blocks x 512 threads (8 waves, wave tile 32 rows x 32 cols).
// LDS: A bf16 3 x 4 KB @ 0. Epilogue overlays: G bf16 16 KB @ 0,
// x fp32 32 KB @ 16384, scale @ 49152, beta @ 49280. Total 49408 B.
// ---------------------------------------------------------------------------
#define MFMA16(a, b, c) __builtin_amdgcn_mfma_f32_16x16x32_bf16(a, b, c, 0, 0, 0)
#define AB(c) (smem + (c) * 4096)

// B-frag register loads, straight from xbt (L2-hot). dst[kb][nf].
#define LOADB(dst, sv)                                                         \
  _Pragma("unroll") for (int kb_ = 0; kb_ < 2; ++kb_)                          \
  _Pragma("unroll") for (int nf_ = 0; nf_ < 2; ++nf_)                          \
      dst[kb_][nf_] = *(const short8*)(bgl + (size_t)(sv) * 16384 +            \
                                       kb_ * 8192 + nf_ * 512);

#define COPYB()                                                                \
  _Pragma("unroll") for (int kb_ = 0; kb_ < 2; ++kb_)                          \
  _Pragma("unroll") for (int nf_ = 0; nf_ < 2; ++nf_) bc[kb_][nf_] = bn[kb_][nf_];

// pack+write A(step) from areg_w into buffer cw; exact fp32 rowsum pre-pack.
#define WRITE_A(cw)                                                            \
  {                                                                            \
    rsum += (areg_w.x + areg_w.y) + (areg_w.z + areg_w.w);                     \
    bf16x4 pk_;                                                                \
    pk_[0] = (short)f2bf(areg_w.x);                                            \
    pk_[1] = (short)f2bf(areg_w.y);                                            \
    pk_[2] = (short)f2bf(areg_w.z);                                            \
    pk_[3] = (short)f2bf(areg_w.w);                                            \
    *(bf16x4*)(AB(cw) + awoff) = pk_;                                          \
  }

#define COMPUTE(c)                                                             \
  {                                                                            \
    const char* Ab_ = AB(c);                                                   \
    short8 a00 = *(const short8*)(Ab_ + aoff00);  /* (mf0,kb0) */              \
    short8 a01 = *(const short8*)(Ab_ + aoff01);  /* (mf0,kb1) */              \
    short8 a10 = *(const short8*)(Ab_ + aoff10);  /* (mf1,kb0) */              \
    short8 a11 = *(const short8*)(Ab_ + aoff11);  /* (mf1,kb1) */              \
    acc[0][0] = MFMA16(a00, bc[0][0], acc[0][0]);                              \
    acc[0][1] = MFMA16(a00, bc[0][1], acc[0][1]);                              \
    acc[1][0] = MFMA16(a10, bc[0][0], acc[1][0]);                              \
    acc[1][1] = MFMA16(a10, bc[0][1], acc[1][1]);                              \
    acc[0][0] = MFMA16(a01, bc[1][0], acc[0][0]);                              \
    acc[0][1] = MFMA16(a01, bc[1][1], acc[0][1]);                              \
    acc[1][0] = MFMA16(a11, bc[1][0], acc[1][0]);                              \
    acc[1][1] = MFMA16(a11, bc[1][1], acc[1][1]);                              \
  }

// One K-step: prefetch B(s+1)->bn and A(s+2)->areg_l BEFORE the barrier;
// after {lgkmcnt(0); barrier} (publishes A(s) ds_writes): write A(s+1),
// compute step s from buffer c with bc=B(s).
// Race audit: buf cw=(s+1)%3 was last ds_read at iter s-2; those reads retired
// before that wave's barrier at iter s-1 (its lgkmcnt(0)) -> write at iter s is
// two barriers later. All waits on areg_w/bc are compiler-counted vmcnt.
#define FULL_ITER(sv, c, cw)                                                   \
  LOADB(bn, (sv) + 1);                                                         \
  areg_l = *(const floatx4*)(agl + (size_t)((sv) + 2) * BK);                   \
  asm volatile("s_waitcnt lgkmcnt(0)\n\ts_barrier" ::: "memory");              \
  WRITE_A(cw);                                                                 \
  COMPUTE(c);                                                                  \
  COPYB();                                                                     \
  areg_w = areg_l;

__global__ __launch_bounds__(512, 2) void fused_kernel(
    const float* __restrict__ adj, const unsigned short* __restrict__ xbt,
    const float* __restrict__ x, const float* __restrict__ beta,
    const float* __restrict__ bias, const unsigned short* __restrict__ wbt,
    float* __restrict__ out) {
  __shared__ __attribute__((aligned(16))) char smem[49408];
  float* sscale = (float*)(smem + 49152);
  float* sbeta  = (float*)(smem + 49280);

  const int tid = threadIdx.x;
  const int w   = tid >> 6;      // 0..7 (wave = one 32-col N strip)
  const int l   = tid & 63;
  const int kq  = l >> 4;        // MFMA k-quad
  const int ml  = l & 15;
  const int m0  = blockIdx.x * 32;

  // ---- A staging geometry (reg-stage -> bf16 ds_write_b64) ----
  // thread t: row = t>>4 (0..31), 4 floats at k-group g4 = t&15.
  const int arow = tid >> 4;
  const int ag4  = tid & 15;
  const float* agl = adj + (size_t)(m0 + arow) * N_NODES + ag4 * 4;
  // A-tile bf16 [32 rows][64 k] = 128 B/row, 8 x 16B chunks, slot = j^(row&7).
  const int awoff = arow * 128 + (((ag4 >> 1) ^ (arow & 7)) << 4) + (ag4 & 1) * 8;

  // A-frag byte offsets: frag(mf,kb): row = mf*16+ml, chunk j = kb*4+kq.
  const int aoff00 = (0 * 16 + ml) * 128 + (((0 * 4 + kq) ^ (ml & 7)) << 4);
  const int aoff01 = (0 * 16 + ml) * 128 + (((1 * 4 + kq) ^ (ml & 7)) << 4);
  const int aoff10 = (1 * 16 + ml) * 128 + (((0 * 4 + kq) ^ (ml & 7)) << 4);
  const int aoff11 = (1 * 16 + ml) * 128 + (((1 * 4 + kq) ^ (ml & 7)) << 4);

  // ---- B geometry: direct global reads. n16 = w*2 + nf (wave owns 32 cols).
  const unsigned short* bgl = xbt + w * 1024 + kq * 128 + ml * 8;

  floatx4 acc[2][2];
  const floatx4 zf4 = {0.f, 0.f, 0.f, 0.f};
  acc[0][0] = zf4; acc[0][1] = zf4; acc[1][0] = zf4; acc[1][1] = zf4;
  float rsum = 0.f;
  floatx4 areg_w, areg_l;
  short8 bc[2][2], bn[2][2];

  // ---- prologue: A(0) -> buf0, bc = B(0), areg_w = A(1) ----
  {
    floatx4 a0v = *(const floatx4*)(agl);
    LOADB(bc, 0);
    areg_w = *(const floatx4*)(agl + BK);
    rsum += (a0v.x + a0v.y) + (a0v.z + a0v.w);
    bf16x4 pk;
    pk[0] = (short)f2bf(a0v.x);
    pk[1] = (short)f2bf(a0v.y);
    pk[2] = (short)f2bf(a0v.z);
    pk[3] = (short)f2bf(a0v.w);
    *(bf16x4*)(AB(0) + awoff) = pk;
  }

  // ---- main loop: s = 0..125 (42 x 3, literal buffer indices) ----
  for (int t = 0; t < 42; ++t) {
    const int s0 = 3 * t;
    FULL_ITER(s0,     0, 1);
    FULL_ITER(s0 + 1, 1, 2);
    FULL_ITER(s0 + 2, 2, 0);
  }
  // s = 126 (c=0): B(127) prefetch; write A(127); nothing left to load
  LOADB(bn, 127);
  asm volatile("s_waitcnt lgkmcnt(0)\n\ts_barrier" ::: "memory");
  WRITE_A(1);
  COMPUTE(0);
  COPYB();
  // s = 127 (c=1)
  asm volatile("s_waitcnt lgkmcnt(0)\n\ts_barrier" ::: "memory");
  COMPUTE(1);

  __syncthreads();   // full drain; LDS reusable by epilogue overlays

  // ---- epilogue (R2-verified mapping) ----
  // stage x-tile (32 rows x 256 fp32 = 32 KB) @ smem+16384, linear
  {
    const float* xs = x + (size_t)m0 * F_DIM + tid * 4;
    char* xd = smem + 16384 + (w << 10);
#pragma unroll
    for (int q = 0; q < 4; ++q) ASYNC16(xs + q * 2048, xd + q * 8192);
  }
  // exact fp32 rowsum: thread partial covers row = w*4 + (l>>4); reduce the
  // 16 lanes (ml) of each row-group.
  {
    float rs = rsum;
    rs += __shfl_xor(rs, 1);
    rs += __shfl_xor(rs, 2);
    rs += __shfl_xor(rs, 4);
    rs += __shfl_xor(rs, 8);
    if ((l & 15) == 0) {
      int row = w * 4 + (l >> 4);
      float b = beta[m0 + row];
      sbeta[row]  = b;
      sscale[row] = 1.0f / (rs + b);
    }
  }
  __syncthreads();   // x landed (syncthreads drains vmcnt), scale/beta visible

  // g = scale*(acc + beta*x) -> bf16 -> G @ smem, 16B-chunk XOR swizzle by row
  const float* xl = (const float*)(smem + 16384);
  unsigned short* G = (unsigned short*)smem;
#pragma unroll
  for (int nf = 0; nf < 2; ++nf) {
    int col = w * 32 + nf * 16 + ml;
    int chunk = col >> 3;            // 0..31
#pragma unroll
    for (int mf = 0; mf < 2; ++mf)
#pragma unroll
      for (int r = 0; r < 4; ++r) {
        int row = mf * 16 + kq * 4 + r;   // C/D layout: col=lane&15, row=quad*4+reg
        float g = sscale[row] * (acc[mf][nf][r] + sbeta[row] * xl[row * F_DIM + col]);
        int slot = (chunk & 24) | ((chunk ^ row) & 7);
        G[row * 256 + slot * 8 + (col & 7)] = f2bf(g);
      }
  }
  __syncthreads();

  // GEMM2: out = g @ W + bias  (W-frags straight from L2-hot wbt)
  floatx4 acc2[2][2];
  acc2[0][0] = zf4; acc2[0][1] = zf4; acc2[1][0] = zf4; acc2[1][1] = zf4;
#pragma unroll
  for (int s2 = 0; s2 < 8; ++s2) {
    int c = s2 * 4 + kq;
    int sl = (c & 24) | ((c ^ ml) & 7);   // rows ml and 16+ml share low-3 XOR
    short8 ag0 = *(const short8*)(G + (ml)      * 256 + sl * 8);
    short8 ag1 = *(const short8*)(G + (16 + ml) * 256 + sl * 8);
    const unsigned short* wb = wbt + s2 * 8192 + (w * 2) * 512 + kq * 128 + ml * 8;
    short8 wv0 = *(const short8*)(wb);
    short8 wv1 = *(const short8*)(wb + 512);
    acc2[0][0] = MFMA16(ag0, wv0, acc2[0][0]);
    acc2[1][0] = MFMA16(ag1, wv0, acc2[1][0]);
    acc2[0][1] = MFMA16(ag0, wv1, acc2[0][1]);
    acc2[1][1] = MFMA16(ag1, wv1, acc2[1][1]);
  }
#pragma unroll
  for (int nf = 0; nf < 2; ++nf) {
    int col = w * 32 + nf * 16 + ml;
    float bv = bias[col];
#pragma unroll
    for (int mf = 0; mf < 2; ++mf)
#pragma unroll
      for (int r = 0; r < 4; ++r) {
        int row = m0 + mf * 16 + kq * 4 + r;
        out[(size_t)row * F_DIM + col] = acc2[mf][nf][r] + bv;
      }
  }
}

// ---------------------------------------------------------------------------
extern "C" void kernel_launch(void* const* d_in, const int* in_sizes, int n_in,
                              void* d_out, int out_size, void* d_ws, size_t ws_size,
                              hipStream_t stream) {
  const float* x    = (const float*)d_in[0];  // [8192][256]
  const float* adj  = (const float*)d_in[1];  // [8192][8192]
  const float* kern = (const float*)d_in[2];  // [256][256]
  const float* bias = (const float*)d_in[3];  // [256]
  const float* beta = (const float*)d_in[4];  // [8192]
  float* out = (float*)d_out;

  char* ws = (char*)d_ws;
  unsigned short* xbt = (unsigned short*)ws;                 // 4 MB
  unsigned short* wbt = xbt + (size_t)N_NODES * F_DIM;       // 128 KB

  tile_bf16_kernel<<<(N_NODES * F_DIM / 8) / 256, 256, 0, stream>>>(x, xbt, N_NODES);
  tile_bf16_kernel<<<(F_DIM * F_DIM / 8) / 256, 256, 0, stream>>>(kern, wbt, F_DIM);
  fused_kernel<<<256, 512, 0, stream>>>(adj, xbt, x, beta, bias, wbt, out);
}

// Round 6
// 417.870 us; speedup vs baseline: 1.0534x; 1.0255x over previous
//
#include <hip/hip_runtime.h>
#include <hip/hip_bf16.h>

// GraphConvolutionLayer on MI355X (gfx950) — fused single-pass, BK=256
// (DRAM-burst-friendly adj streaming).
//   scale = 1/(rowsum(adj)+beta);  agg = adj@x + beta*x;  out = (scale*agg)@W + bias
// Evidence (R0-R5): every structure (two-stage, fused all-LDS, fused LDS-lean)
// sits at ~100-110 us for the adj stream = ~40% HBM. Invariance across on-chip
// structure => DRAM activation-bound: BK=64 visits each of 8192 concurrent row
// streams for only 256 B per visit -> page reopen per burst. This round:
//   - BK=256: 1 KB contiguous per row per visit (4x fewer activates/byte).
//   - Wave geometry unchanged from R5 (512 thr, 8 waves, wave = 32 rows x 32
//     cols, acc 2x2): B-frags JIT from L2-hot xbt (2-deep kb rolling regs),
//     A reg-staged fp32->bf16 into XOR-swizzled LDS (16 KB x 3 bufs, literal
//     indices), exact fp32 rowsum pre-pack.
//   - 32 K-steps, ONE {lgkmcnt(0); s_barrier} per ~3200-cyc step; zero
//     global_load_lds in the K-loop; all vmcnt waits compiler-counted.
//   - Budgets: LDS ~144 KB/step (~45 B/cyc vs 85+), B-L2 40 B/cyc (<56),
//     A-prefetch 2 steps (~6400 cyc slack vs ~900 HBM latency).
// Epilogue (x-stage, scale/beta, G-swizzle, GEMM2 vs wbt) verbatim from R5
// (hardware-verified, absmax 4.88e-4).

typedef __attribute__((ext_vector_type(8))) short  short8;
typedef __attribute__((ext_vector_type(4))) float  floatx4;

#define N_NODES 8192
#define F_DIM   256
#define BK      256
#define NSTEPS  (N_NODES / BK)   // 32

#define ASYNC16(g, l)                                                          \
  __builtin_amdgcn_global_load_lds(                                           \
      (const __attribute__((address_space(1))) void*)(g),                     \
      (__attribute__((address_space(3))) void*)(l), 16, 0, 0)

// fp32 -> bf16 round-to-nearest-even (no NaN handling; inputs are finite)
__device__ __forceinline__ unsigned short f2bf(float f) {
  unsigned u = __float_as_uint(f);
  return (unsigned short)((u + 0x7FFFu + ((u >> 16) & 1u)) >> 16);
}

__device__ __forceinline__ short8 pack_bf16x8(floatx4 a, floatx4 b) {
  short8 r;
  r[0] = (short)f2bf(a.x);
  r[1] = (short)f2bf(a.y);
  r[2] = (short)f2bf(a.z);
  r[3] = (short)f2bf(a.w);
  r[4] = (short)f2bf(b.x);
  r[5] = (short)f2bf(b.y);
  r[6] = (short)f2bf(b.z);
  r[7] = (short)f2bf(b.w);
  return r;
}

// ---------------------------------------------------------------------------
// k1: fp32 [K][256] -> bf16 tiled [K/32][n16(16)][kg(4)][nl(16)][8]
// ---------------------------------------------------------------------------
__global__ __launch_bounds__(256) void tile_bf16_kernel(
    const float* __restrict__ src, unsigned short* __restrict__ dst, int K) {
  const int Nn = F_DIM;
  int cid = blockIdx.x * 256 + threadIdx.x;      // one 8-element chunk
  int per_kblk = Nn * 4;                         // 1024 chunks per 32-k block
  int kblk = cid / per_kblk;
  int rem  = cid - kblk * per_kblk;
  int n16 = rem >> 6;
  int kg  = (rem >> 4) & 3;
  int nl  = rem & 15;
  int n = n16 * 16 + nl;
  int k = kblk * 32 + kg * 8;
  const float* s = src + (size_t)k * Nn + n;
  floatx4 v0, v1;
  v0.x = s[0];
  v0.y = s[(size_t)Nn];
  v0.z = s[(size_t)2 * Nn];
  v0.w = s[(size_t)3 * Nn];
  v1.x = s[(size_t)4 * Nn];
  v1.y = s[(size_t)5 * Nn];
  v1.z = s[(size_t)6 * Nn];
  v1.w = s[(size_t)7 * Nn];
  *(short8*)(dst + (size_t)cid * 8) = pack_bf16x8(v0, v1);
}

// ---------------------------------------------------------------------------
// k2: fused  agg + rowsum + scale + W-GEMM
// grid 256 blocks x 512 threads (8 waves, wave tile 32 rows x 32 cols).
// LDS: A bf16 3 x 16 KB @ 0 (tile [32 rows][256 k], 512 B/row, XOR-swizzled
// 16B chunks). Epilogue overlays: G bf16 16 KB @ 0, x fp32 32 KB @ 16384,
// scale @ 49152, beta @ 49280. Total 49408 B.
// ---------------------------------------------------------------------------
#define MFMA16(a, b, c) __builtin_amdgcn_mfma_f32_16x16x32_bf16(a, b, c, 0, 0, 0)
#define AB(c)  (smem + (c) * 16384)
#define LDB(p) (*(const short8*)(p))
#define BS(sv) (bgl + (size_t)(sv) * 65536)   // step stride: 8 kblks x 8192 shorts

// A-frag byte offset: frag(mf,kb): row = mf*16+ml, chunk j = kb*4+kq (0..31),
// slot = (j&24)|((j^row)&7)  [row&7 == ml&7]
#define AOFF(mf, kb)                                                           \
  (((mf) * 16 + ml) * 512 +                                                    \
   (((((kb) * 4 + kq) & 24) | ((((kb) * 4 + kq) ^ ml) & 7)) << 4))

// pack+write A(step) from aw0..aw3 into buffer cw; exact fp32 rowsum pre-pack.
#define WRITE_A(cw)                                                            \
  {                                                                            \
    rsum += ((aw0.x + aw0.y) + (aw0.z + aw0.w)) +                              \
            ((aw1.x + aw1.y) + (aw1.z + aw1.w)) +                              \
            ((aw2.x + aw2.y) + (aw2.z + aw2.w)) +                              \
            ((aw3.x + aw3.y) + (aw3.z + aw3.w));                               \
    *(short8*)(AB(cw) + awoff0) = pack_bf16x8(aw0, aw1);                       \
    *(short8*)(AB(cw) + awoff1) = pack_bf16x8(aw2, aw3);                       \
  }

// one kb slice: 2 A-frag LDS reads, JIT-prefetch next kb's B pair, 4 MFMA
#define KB(kb)                                                                 \
  a0_ = *(const short8*)(Ab_ + AOFF(0, kb));                                   \
  a1_ = *(const short8*)(Ab_ + AOFF(1, kb));                                   \
  n0_ = LDB(Bsv_ + ((kb) + 1) * 8192);                                         \
  n1_ = LDB(Bsv_ + ((kb) + 1) * 8192 + 512);                                   \
  acc[0][0] = MFMA16(a0_, b0_, acc[0][0]);                                     \
  acc[0][1] = MFMA16(a0_, b1_, acc[0][1]);                                     \
  acc[1][0] = MFMA16(a1_, b0_, acc[1][0]);                                     \
  acc[1][1] = MFMA16(a1_, b1_, acc[1][1]);                                     \
  b0_ = n0_; b1_ = n1_;

#define KBLAST(kb)                                                             \
  a0_ = *(const short8*)(Ab_ + AOFF(0, kb));                                   \
  a1_ = *(const short8*)(Ab_ + AOFF(1, kb));                                   \
  acc[0][0] = MFMA16(a0_, b0_, acc[0][0]);                                     \
  acc[0][1] = MFMA16(a0_, b1_, acc[0][1]);                                     \
  acc[1][0] = MFMA16(a1_, b0_, acc[1][0]);                                     \
  acc[1][1] = MFMA16(a1_, b1_, acc[1][1]);

#define COMPUTE(c, sv)                                                         \
  {                                                                            \
    const char* Ab_ = AB(c);                                                   \
    const unsigned short* Bsv_ = BS(sv);                                       \
    short8 b0_ = pb0, b1_ = pb1;                                               \
    short8 a0_, a1_, n0_, n1_;                                                 \
    KB(0) KB(1) KB(2) KB(3) KB(4) KB(5) KB(6) KBLAST(7)                        \
  }

// One K-step: prefetch A(s+2)->al and B(s) kb0-pair BEFORE the barrier; after
// {lgkmcnt(0); barrier} (publishes A(s) ds_writes): write A(s+1) into cw,
// compute step s from buffer c. Race audit: buf cw=(s+1)%3 was last ds_read at
// iter s-2; those reads retired before that wave's lgkmcnt(0)+barrier at iter
// s-1 -> write at iter s is one barrier later. All global waits compiler-counted.
#define FULL_ITER(sv, c, cw)                                                   \
  al0 = *(const floatx4*)(agp + (size_t)((sv) + 2) * BK);                      \
  al1 = *(const floatx4*)(agp + (size_t)((sv) + 2) * BK + 4);                  \
  al2 = *(const floatx4*)(agp + (size_t)((sv) + 2) * BK + 8);                  \
  al3 = *(const floatx4*)(agp + (size_t)((sv) + 2) * BK + 12);                 \
  pb0 = LDB(BS(sv));                                                           \
  pb1 = LDB(BS(sv) + 512);                                                     \
  asm volatile("s_waitcnt lgkmcnt(0)\n\ts_barrier" ::: "memory");              \
  WRITE_A(cw);                                                                 \
  COMPUTE(c, sv);                                                              \
  aw0 = al0; aw1 = al1; aw2 = al2; aw3 = al3;

__global__ __launch_bounds__(512, 1) void fused_kernel(
    const float* __restrict__ adj, const unsigned short* __restrict__ xbt,
    const float* __restrict__ x, const float* __restrict__ beta,
    const float* __restrict__ bias, const unsigned short* __restrict__ wbt,
    float* __restrict__ out) {
  __shared__ __attribute__((aligned(16))) char smem[49408];
  float* sscale = (float*)(smem + 49152);
  float* sbeta  = (float*)(smem + 49280);

  const int tid = threadIdx.x;
  const int w   = tid >> 6;      // 0..7 (wave = one 32-col N strip)
  const int l   = tid & 63;
  const int kq  = l >> 4;        // MFMA k-quad
  const int ml  = l & 15;
  const int m0  = blockIdx.x * 32;

  // ---- A staging geometry (reg-stage 64 B/thread -> 2 x b128 ds_write) ----
  // thread t: row = t>>4 (0..31), 16 floats at k = (t&15)*16 (+ step*256).
  const int arow = tid >> 4;
  const int aq   = tid & 15;
  const float* agp = adj + (size_t)(m0 + arow) * N_NODES + aq * 16;
  // bf16 chunks j0 = 2*aq, j1 = 2*aq+1; slot = (j&24)|((j^row)&7)
  const int j0 = aq * 2, j1 = aq * 2 + 1;
  const int awoff0 = arow * 512 + (((j0 & 24) | ((j0 ^ arow) & 7)) << 4);
  const int awoff1 = arow * 512 + (((j1 & 24) | ((j1 ^ arow) & 7)) << 4);

  // ---- B geometry: direct global reads. n16 = w*2 + nf (wave owns 32 cols).
  const unsigned short* bgl = xbt + w * 1024 + kq * 128 + ml * 8;

  floatx4 acc[2][2];
  const floatx4 zf4 = {0.f, 0.f, 0.f, 0.f};
  acc[0][0] = zf4; acc[0][1] = zf4; acc[1][0] = zf4; acc[1][1] = zf4;
  float rsum = 0.f;
  floatx4 aw0, aw1, aw2, aw3, al0, al1, al2, al3;
  short8 pb0, pb1;

  // ---- prologue: A(0) -> buf0 (direct), aw = A(1) ----
  aw0 = *(const floatx4*)(agp);
  aw1 = *(const floatx4*)(agp + 4);
  aw2 = *(const floatx4*)(agp + 8);
  aw3 = *(const floatx4*)(agp + 12);
  WRITE_A(0);
  aw0 = *(const floatx4*)(agp + BK);
  aw1 = *(const floatx4*)(agp + BK + 4);
  aw2 = *(const floatx4*)(agp + BK + 8);
  aw3 = *(const floatx4*)(agp + BK + 12);

  // ---- main loop: s = 0..29 (10 x 3, literal buffer indices) ----
  for (int t = 0; t < 10; ++t) {
    const int s0 = 3 * t;
    FULL_ITER(s0,     0, 1);
    FULL_ITER(s0 + 1, 1, 2);
    FULL_ITER(s0 + 2, 2, 0);
  }
  // s = 30 (c=0): write A(31) -> buf1; nothing left to load from adj
  pb0 = LDB(BS(30));
  pb1 = LDB(BS(30) + 512);
  asm volatile("s_waitcnt lgkmcnt(0)\n\ts_barrier" ::: "memory");
  WRITE_A(1);
  COMPUTE(0, 30);
  // s = 31 (c=1)
  pb0 = LDB(BS(31));
  pb1 = LDB(BS(31) + 512);
  asm volatile("s_waitcnt lgkmcnt(0)\n\ts_barrier" ::: "memory");
  COMPUTE(1, 31);

  __syncthreads();   // full drain; LDS reusable by epilogue overlays

  // ---- epilogue (R5-verified, verbatim) ----
  // stage x-tile (32 rows x 256 fp32 = 32 KB) @ smem+16384, linear
  {
    const float* xs = x + (size_t)m0 * F_DIM + tid * 4;
    char* xd = smem + 16384 + (w << 10);
#pragma unroll
    for (int q = 0; q < 4; ++q) ASYNC16(xs + q * 2048, xd + q * 8192);
  }
  // exact fp32 rowsum: thread partial covers row = w*4 + (l>>4); reduce the
  // 16 lanes (ml) of each row-group.
  {
    float rs = rsum;
    rs += __shfl_xor(rs, 1);
    rs += __shfl_xor(rs, 2);
    rs += __shfl_xor(rs, 4);
    rs += __shfl_xor(rs, 8);
    if ((l & 15) == 0) {
      int row = w * 4 + (l >> 4);
      float b = beta[m0 + row];
      sbeta[row]  = b;
      sscale[row] = 1.0f / (rs + b);
    }
  }
  __syncthreads();   // x landed (syncthreads drains vmcnt), scale/beta visible

  // g = scale*(acc + beta*x) -> bf16 -> G @ smem, 16B-chunk XOR swizzle by row
  const float* xl = (const float*)(smem + 16384);
  unsigned short* G = (unsigned short*)smem;
#pragma unroll
  for (int nf = 0; nf < 2; ++nf) {
    int col = w * 32 + nf * 16 + ml;
    int chunk = col >> 3;            // 0..31
#pragma unroll
    for (int mf = 0; mf < 2; ++mf)
#pragma unroll
      for (int r = 0; r < 4; ++r) {
        int row = mf * 16 + kq * 4 + r;   // C/D layout: col=lane&15, row=quad*4+reg
        float g = sscale[row] * (acc[mf][nf][r] + sbeta[row] * xl[row * F_DIM + col]);
        int slot = (chunk & 24) | ((chunk ^ row) & 7);
        G[row * 256 + slot * 8 + (col & 7)] = f2bf(g);
      }
  }
  __syncthreads();

  // GEMM2: out = g @ W + bias  (W-frags straight from L2-hot wbt)
  floatx4 acc2[2][2];
  acc2[0][0] = zf4; acc2[0][1] = zf4; acc2[1][0] = zf4; acc2[1][1] = zf4;
#pragma unroll
  for (int s2 = 0; s2 < 8; ++s2) {
    int c = s2 * 4 + kq;
    int sl = (c & 24) | ((c ^ ml) & 7);   // rows ml and 16+ml share low-3 XOR
    short8 ag0 = *(const short8*)(G + (ml)      * 256 + sl * 8);
    short8 ag1 = *(const short8*)(G + (16 + ml) * 256 + sl * 8);
    const unsigned short* wb = wbt + s2 * 8192 + (w * 2) * 512 + kq * 128 + ml * 8;
    short8 wv0 = *(const short8*)(wb);
    short8 wv1 = *(const short8*)(wb + 512);
    acc2[0][0] = MFMA16(ag0, wv0, acc2[0][0]);
    acc2[1][0] = MFMA16(ag1, wv0, acc2[1][0]);
    acc2[0][1] = MFMA16(ag0, wv1, acc2[0][1]);
    acc2[1][1] = MFMA16(ag1, wv1, acc2[1][1]);
  }
#pragma unroll
  for (int nf = 0; nf < 2; ++nf) {
    int col = w * 32 + nf * 16 + ml;
    float bv = bias[col];
#pragma unroll
    for (int mf = 0; mf < 2; ++mf)
#pragma unroll
      for (int r = 0; r < 4; ++r) {
        int row = m0 + mf * 16 + kq * 4 + r;
        out[(size_t)row * F_DIM + col] = acc2[mf][nf][r] + bv;
      }
  }
}

// ---------------------------------------------------------------------------
extern "C" void kernel_launch(void* const* d_in, const int* in_sizes, int n_in,
                              void* d_out, int out_size, void* d_ws, size_t ws_size,
                              hipStream_t stream) {
  const float* x    = (const float*)d_in[0];  // [8192][256]
  const float* adj  = (const float*)d_in[1];  // [8192][8192]
  const float* kern = (const float*)d_in[2];  // [256][256]
  const float* bias = (const float*)d_in[3];  // [256]
  const float* beta = (const float*)d_in[4];  // [8192]
  float* out = (float*)d_out;

  char* ws = (char*)d_ws;
  unsigned short* xbt = (unsigned short*)ws;                 // 4 MB
  unsigned short* wbt = xbt + (size_t)N_NODES * F_DIM;       // 128 KB

  tile_bf16_kernel<<<(N_NODES * F_DIM / 8) / 256, 256, 0, stream>>>(x, xbt, N_NODES);
  tile_bf16_kernel<<<(F_DIM * F_DIM / 8) / 256, 256, 0, stream>>>(kern, wbt, F_DIM);
  fused_kernel<<<256, 512, 0, stream>>>(adj, xbt, x, beta, bias, wbt, out);
}

// Round 7
// 411.010 us; speedup vs baseline: 1.0710x; 1.0167x over previous
//
#include <hip/hip_runtime.h>
#include <hip/hip_bf16.h>

// GraphConvolutionLayer on MI355X (gfx950) — fused single-pass, BK=256, with
// half-step-batched B prefetch (R7).
//   scale = 1/(rowsum(adj)+beta);  agg = adj@x + beta*x;  out = (scale*agg)@W + bias
// Evidence (R0-R6): all structures ~95-110 us for the 268 MB adj stream (~2x
// floor). R6 (BK=256) gained 10 us -> DRAM bursts were secondary. Remaining
// theory: B-frag loads from L2-hot xbt had only ~1-slice (~50 cyc) lookahead
// vs ~200-400 cyc L2/L3 latency -> ~150-300 cyc stall per kb-slice x 8/step.
// R7: phase-batched B prefetch, issued one 4-slice phase (200-500 cyc) early:
//   barrier -> issue q=slices4-7(s) -> WRITE_A -> compute p=slices0-3(s)
//           -> issue p=slices0-3(s+1) -> compute q=slices4-7(s)
// 16 live short8 B-regs (64 VGPR); all waits compiler-counted (loads are pure
// VGPR targets, no LDS hazard, no manual vmcnt). Geometry/epilogue = R6
// verbatim (hardware-verified, absmax 4.88e-4).

typedef __attribute__((ext_vector_type(8))) short  short8;
typedef __attribute__((ext_vector_type(4))) float  floatx4;

#define N_NODES 8192
#define F_DIM   256
#define BK      256
#define NSTEPS  (N_NODES / BK)   // 32

#define ASYNC16(g, l)                                                          \
  __builtin_amdgcn_global_load_lds(                                           \
      (const __attribute__((address_space(1))) void*)(g),                     \
      (__attribute__((address_space(3))) void*)(l), 16, 0, 0)

// fp32 -> bf16 round-to-nearest-even (no NaN handling; inputs are finite)
__device__ __forceinline__ unsigned short f2bf(float f) {
  unsigned u = __float_as_uint(f);
  return (unsigned short)((u + 0x7FFFu + ((u >> 16) & 1u)) >> 16);
}

__device__ __forceinline__ short8 pack_bf16x8(floatx4 a, floatx4 b) {
  short8 r;
  r[0] = (short)f2bf(a.x);
  r[1] = (short)f2bf(a.y);
  r[2] = (short)f2bf(a.z);
  r[3] = (short)f2bf(a.w);
  r[4] = (short)f2bf(b.x);
  r[5] = (short)f2bf(b.y);
  r[6] = (short)f2bf(b.z);
  r[7] = (short)f2bf(b.w);
  return r;
}

// ---------------------------------------------------------------------------
// k1: fp32 [K][256] -> bf16 tiled [K/32][n16(16)][kg(4)][nl(16)][8]
// ---------------------------------------------------------------------------
__global__ __launch_bounds__(256) void tile_bf16_kernel(
    const float* __restrict__ src, unsigned short* __restrict__ dst, int K) {
  const int Nn = F_DIM;
  int cid = blockIdx.x * 256 + threadIdx.x;      // one 8-element chunk
  int per_kblk = Nn * 4;                         // 1024 chunks per 32-k block
  int kblk = cid / per_kblk;
  int rem  = cid - kblk * per_kblk;
  int n16 = rem >> 6;
  int kg  = (rem >> 4) & 3;
  int nl  = rem & 15;
  int n = n16 * 16 + nl;
  int k = kblk * 32 + kg * 8;
  const float* s = src + (size_t)k * Nn + n;
  floatx4 v0, v1;
  v0.x = s[0];
  v0.y = s[(size_t)Nn];
  v0.z = s[(size_t)2 * Nn];
  v0.w = s[(size_t)3 * Nn];
  v1.x = s[(size_t)4 * Nn];
  v1.y = s[(size_t)5 * Nn];
  v1.z = s[(size_t)6 * Nn];
  v1.w = s[(size_t)7 * Nn];
  *(short8*)(dst + (size_t)cid * 8) = pack_bf16x8(v0, v1);
}

// ---------------------------------------------------------------------------
// k2: fused  agg + rowsum + scale + W-GEMM
// grid 256 blocks x 512 threads (8 waves, wave tile 32 rows x 32 cols).
// LDS: A bf16 3 x 16 KB @ 0 ([32 rows][256 k], 512 B/row, XOR-swizzled 16B
// chunks). Epilogue overlays: G bf16 16 KB @ 0, x fp32 32 KB @ 16384,
// scale @ 49152, beta @ 49280. Total 49408 B.
// ---------------------------------------------------------------------------
#define MFMA16(a, b, c) __builtin_amdgcn_mfma_f32_16x16x32_bf16(a, b, c, 0, 0, 0)
#define AB(c)  (smem + (c) * 16384)
#define LDB(p) (*(const short8*)(p))
#define BS(sv) (bgl + (size_t)(sv) * 65536)   // step stride: 8 kblks x 8192 shorts

// A-frag byte offset: frag(mf,kb): row = mf*16+ml, chunk j = kb*4+kq (0..31),
// slot = (j&24)|((j^row)&7)  [row&7 == ml&7]
#define AOFF(mf, kb)                                                           \
  (((mf) * 16 + ml) * 512 +                                                    \
   (((((kb) * 4 + kq) & 24) | ((((kb) * 4 + kq) ^ ml) & 7)) << 4))

// pack+write A(step) from aw0..aw3 into buffer cw; exact fp32 rowsum pre-pack.
#define WRITE_A(cw)                                                            \
  {                                                                            \
    rsum += ((aw0.x + aw0.y) + (aw0.z + aw0.w)) +                              \
            ((aw1.x + aw1.y) + (aw1.z + aw1.w)) +                              \
            ((aw2.x + aw2.y) + (aw2.z + aw2.w)) +                              \
            ((aw3.x + aw3.y) + (aw3.z + aw3.w));                               \
    *(short8*)(AB(cw) + awoff0) = pack_bf16x8(aw0, aw1);                       \
    *(short8*)(AB(cw) + awoff1) = pack_bf16x8(aw2, aw3);                       \
  }

// issue the 8 B-loads (4 kb slices x 2 nf) for step sv, slices kb0..kb0+3
#define ISSUE4(sv, kb0, Ba0, Bb0, Ba1, Bb1, Ba2, Bb2, Ba3, Bb3)                \
  Ba0 = LDB(BS(sv) + ((kb0) + 0) * 8192);                                      \
  Bb0 = LDB(BS(sv) + ((kb0) + 0) * 8192 + 512);                                \
  Ba1 = LDB(BS(sv) + ((kb0) + 1) * 8192);                                      \
  Bb1 = LDB(BS(sv) + ((kb0) + 1) * 8192 + 512);                                \
  Ba2 = LDB(BS(sv) + ((kb0) + 2) * 8192);                                      \
  Bb2 = LDB(BS(sv) + ((kb0) + 2) * 8192 + 512);                                \
  Ba3 = LDB(BS(sv) + ((kb0) + 3) * 8192);                                      \
  Bb3 = LDB(BS(sv) + ((kb0) + 3) * 8192 + 512);

#define SLICE(Ab_, kb, Ba, Bb)                                                 \
  {                                                                            \
    short8 xx0_ = *(const short8*)(Ab_ + AOFF(0, kb));                         \
    short8 xx1_ = *(const short8*)(Ab_ + AOFF(1, kb));                         \
    acc[0][0] = MFMA16(xx0_, Ba, acc[0][0]);                                   \
    acc[0][1] = MFMA16(xx0_, Bb, acc[0][1]);                                   \
    acc[1][0] = MFMA16(xx1_, Ba, acc[1][0]);                                   \
    acc[1][1] = MFMA16(xx1_, Bb, acc[1][1]);                                   \
  }

#define COMP4(c, kb0, Ba0, Bb0, Ba1, Bb1, Ba2, Bb2, Ba3, Bb3)                  \
  {                                                                            \
    const char* Ab_ = AB(c);                                                   \
    SLICE(Ab_, (kb0) + 0, Ba0, Bb0)                                            \
    SLICE(Ab_, (kb0) + 1, Ba1, Bb1)                                            \
    SLICE(Ab_, (kb0) + 2, Ba2, Bb2)                                            \
    SLICE(Ab_, (kb0) + 3, Ba3, Bb3)                                            \
  }

// One K-step. Entering iter sv: p = slices 0-3 of step sv (issued during iter
// sv-1), A(sv) staged in buf c (written iter sv-1), A(sv+1) in aw regs.
// Race audit (unchanged from R6): buf cw=(sv+1)%3 was last ds_read at iter
// sv-2; those reads retired before that wave's lgkmcnt(0)+barrier at iter
// sv-1 -> write at iter sv is one barrier later. B loads are pure VGPR
// targets (no LDS hazard); all waits compiler-counted.
#define FULL_ITER(sv, c, cw)                                                   \
  al0 = *(const floatx4*)(agp + (size_t)((sv) + 2) * BK);                      \
  al1 = *(const floatx4*)(agp + (size_t)((sv) + 2) * BK + 4);                  \
  al2 = *(const floatx4*)(agp + (size_t)((sv) + 2) * BK + 8);                  \
  al3 = *(const floatx4*)(agp + (size_t)((sv) + 2) * BK + 12);                 \
  asm volatile("s_waitcnt lgkmcnt(0)\n\ts_barrier" ::: "memory");              \
  ISSUE4((sv), 4, q0a, q0b, q1a, q1b, q2a, q2b, q3a, q3b)                      \
  WRITE_A(cw);                                                                 \
  COMP4((c), 0, p0a, p0b, p1a, p1b, p2a, p2b, p3a, p3b)                        \
  ISSUE4((sv) + 1, 0, p0a, p0b, p1a, p1b, p2a, p2b, p3a, p3b)                  \
  COMP4((c), 4, q0a, q0b, q1a, q1b, q2a, q2b, q3a, q3b)                        \
  aw0 = al0; aw1 = al1; aw2 = al2; aw3 = al3;

__global__ __launch_bounds__(512, 1) void fused_kernel(
    const float* __restrict__ adj, const unsigned short* __restrict__ xbt,
    const float* __restrict__ x, const float* __restrict__ beta,
    const float* __restrict__ bias, const unsigned short* __restrict__ wbt,
    float* __restrict__ out) {
  __shared__ __attribute__((aligned(16))) char smem[49408];
  float* sscale = (float*)(smem + 49152);
  float* sbeta  = (float*)(smem + 49280);

  const int tid = threadIdx.x;
  const int w   = tid >> 6;      // 0..7 (wave = one 32-col N strip)
  const int l   = tid & 63;
  const int kq  = l >> 4;        // MFMA k-quad
  const int ml  = l & 15;
  const int m0  = blockIdx.x * 32;

  // ---- A staging geometry (reg-stage 64 B/thread -> 2 x b128 ds_write) ----
  // thread t: row = t>>4 (0..31), 16 floats at k = (t&15)*16 (+ step*256).
  const int arow = tid >> 4;
  const int aq   = tid & 15;
  const float* agp = adj + (size_t)(m0 + arow) * N_NODES + aq * 16;
  // bf16 chunks j0 = 2*aq, j1 = 2*aq+1; slot = (j&24)|((j^row)&7)
  const int j0 = aq * 2, j1 = aq * 2 + 1;
  const int awoff0 = arow * 512 + (((j0 & 24) | ((j0 ^ arow) & 7)) << 4);
  const int awoff1 = arow * 512 + (((j1 & 24) | ((j1 ^ arow) & 7)) << 4);

  // ---- B geometry: direct global reads. n16 = w*2 + nf (wave owns 32 cols).
  const unsigned short* bgl = xbt + w * 1024 + kq * 128 + ml * 8;

  floatx4 acc[2][2];
  const floatx4 zf4 = {0.f, 0.f, 0.f, 0.f};
  acc[0][0] = zf4; acc[0][1] = zf4; acc[1][0] = zf4; acc[1][1] = zf4;
  float rsum = 0.f;
  floatx4 aw0, aw1, aw2, aw3, al0, al1, al2, al3;
  short8 p0a, p0b, p1a, p1b, p2a, p2b, p3a, p3b;
  short8 q0a, q0b, q1a, q1b, q2a, q2b, q3a, q3b;

  // ---- prologue: B slices 0-3 of step 0 early; A(0) -> buf0; aw = A(1) ----
  ISSUE4(0, 0, p0a, p0b, p1a, p1b, p2a, p2b, p3a, p3b)
  aw0 = *(const floatx4*)(agp);
  aw1 = *(const floatx4*)(agp + 4);
  aw2 = *(const floatx4*)(agp + 8);
  aw3 = *(const floatx4*)(agp + 12);
  WRITE_A(0);
  aw0 = *(const floatx4*)(agp + BK);
  aw1 = *(const floatx4*)(agp + BK + 4);
  aw2 = *(const floatx4*)(agp + BK + 8);
  aw3 = *(const floatx4*)(agp + BK + 12);

  // ---- main loop: s = 0..29 (10 x 3, literal buffer indices) ----
  for (int t = 0; t < 10; ++t) {
    const int s0 = 3 * t;
    FULL_ITER(s0,     0, 1);
    FULL_ITER(s0 + 1, 1, 2);
    FULL_ITER(s0 + 2, 2, 0);
  }
  // s = 30 (c=0, cw=1): write A(31); nothing left to load from adj
  asm volatile("s_waitcnt lgkmcnt(0)\n\ts_barrier" ::: "memory");
  ISSUE4(30, 4, q0a, q0b, q1a, q1b, q2a, q2b, q3a, q3b)
  WRITE_A(1);
  COMP4(0, 0, p0a, p0b, p1a, p1b, p2a, p2b, p3a, p3b)
  ISSUE4(31, 0, p0a, p0b, p1a, p1b, p2a, p2b, p3a, p3b)
  COMP4(0, 4, q0a, q0b, q1a, q1b, q2a, q2b, q3a, q3b)
  // s = 31 (c=1)
  asm volatile("s_waitcnt lgkmcnt(0)\n\ts_barrier" ::: "memory");
  ISSUE4(31, 4, q0a, q0b, q1a, q1b, q2a, q2b, q3a, q3b)
  COMP4(1, 0, p0a, p0b, p1a, p1b, p2a, p2b, p3a, p3b)
  COMP4(1, 4, q0a, q0b, q1a, q1b, q2a, q2b, q3a, q3b)

  __syncthreads();   // full drain; LDS reusable by epilogue overlays

  // ---- epilogue (R5/R6-verified, verbatim) ----
  // stage x-tile (32 rows x 256 fp32 = 32 KB) @ smem+16384, linear
  {
    const float* xs = x + (size_t)m0 * F_DIM + tid * 4;
    char* xd = smem + 16384 + (w << 10);
#pragma unroll
    for (int q = 0; q < 4; ++q) ASYNC16(xs + q * 2048, xd + q * 8192);
  }
  // exact fp32 rowsum: thread partial covers row = w*4 + (l>>4); reduce the
  // 16 lanes (ml) of each row-group.
  {
    float rs = rsum;
    rs += __shfl_xor(rs, 1);
    rs += __shfl_xor(rs, 2);
    rs += __shfl_xor(rs, 4);
    rs += __shfl_xor(rs, 8);
    if ((l & 15) == 0) {
      int row = w * 4 + (l >> 4);
      float b = beta[m0 + row];
      sbeta[row]  = b;
      sscale[row] = 1.0f / (rs + b);
    }
  }
  __syncthreads();   // x landed (syncthreads drains vmcnt), scale/beta visible

  // g = scale*(acc + beta*x) -> bf16 -> G @ smem, 16B-chunk XOR swizzle by row
  const float* xl = (const float*)(smem + 16384);
  unsigned short* G = (unsigned short*)smem;
#pragma unroll
  for (int nf = 0; nf < 2; ++nf) {
    int col = w * 32 + nf * 16 + ml;
    int chunk = col >> 3;            // 0..31
#pragma unroll
    for (int mf = 0; mf < 2; ++mf)
#pragma unroll
      for (int r = 0; r < 4; ++r) {
        int row = mf * 16 + kq * 4 + r;   // C/D layout: col=lane&15, row=quad*4+reg
        float g = sscale[row] * (acc[mf][nf][r] + sbeta[row] * xl[row * F_DIM + col]);
        int slot = (chunk & 24) | ((chunk ^ row) & 7);
        G[row * 256 + slot * 8 + (col & 7)] = f2bf(g);
      }
  }
  __syncthreads();

  // GEMM2: out = g @ W + bias  (W-frags straight from L2-hot wbt)
  floatx4 acc2[2][2];
  acc2[0][0] = zf4; acc2[0][1] = zf4; acc2[1][0] = zf4; acc2[1][1] = zf4;
#pragma unroll
  for (int s2 = 0; s2 < 8; ++s2) {
    int c = s2 * 4 + kq;
    int sl = (c & 24) | ((c ^ ml) & 7);   // rows ml and 16+ml share low-3 XOR
    short8 ag0 = *(const short8*)(G + (ml)      * 256 + sl * 8);
    short8 ag1 = *(const short8*)(G + (16 + ml) * 256 + sl * 8);
    const unsigned short* wb = wbt + s2 * 8192 + (w * 2) * 512 + kq * 128 + ml * 8;
    short8 wv0 = *(const short8*)(wb);
    short8 wv1 = *(const short8*)(wb + 512);
    acc2[0][0] = MFMA16(ag0, wv0, acc2[0][0]);
    acc2[1][0] = MFMA16(ag1, wv0, acc2[1][0]);
    acc2[0][1] = MFMA16(ag0, wv1, acc2[0][1]);
    acc2[1][1] = MFMA16(ag1, wv1, acc2[1][1]);
  }
#pragma unroll
  for (int nf = 0; nf < 2; ++nf) {
    int col = w * 32 + nf * 16 + ml;
    float bv = bias[col];
#pragma unroll
    for (int mf = 0; mf < 2; ++mf)
#pragma unroll
      for (int r = 0; r < 4; ++r) {
        int row = m0 + mf * 16 + kq * 4 + r;
        out[(size_t)row * F_DIM + col] = acc2[mf][nf][r] + bv;
      }
  }
}

// ---------------------------------------------------------------------------
extern "C" void kernel_launch(void* const* d_in, const int* in_sizes, int n_in,
                              void* d_out, int out_size, void* d_ws, size_t ws_size,
                              hipStream_t stream) {
  const float* x    = (const float*)d_in[0];  // [8192][256]
  const float* adj  = (const float*)d_in[1];  // [8192][8192]
  const float* kern = (const float*)d_in[2];  // [256][256]
  const float* bias = (const float*)d_in[3];  // [256]
  const float* beta = (const float*)d_in[4];  // [8192]
  float* out = (float*)d_out;

  char* ws = (char*)d_ws;
  unsigned short* xbt = (unsigned short*)ws;                 // 4 MB
  unsigned short* wbt = xbt + (size_t)N_NODES * F_DIM;       // 128 KB

  tile_bf16_kernel<<<(N_NODES * F_DIM / 8) / 256, 256, 0, stream>>>(x, xbt, N_NODES);
  tile_bf16_kernel<<<(F_DIM * F_DIM / 8) / 256, 256, 0, stream>>>(kern, wbt, F_DIM);
  fused_kernel<<<256, 512, 0, stream>>>(adj, xbt, x, beta, bias, wbt, out);
}